// Round 11
// baseline (290.199 us; speedup 1.0000x reference)
//
#include <hip/hip_runtime.h>
#include <hip/hip_fp16.h>
#include <math.h>

#define NPTS 10000
#define KNN  20
#define F    128
#define KIT  40            // iterations of 256 candidates
#define PTS_PAD 10496      // KIT*256 + 256 so prefetch never goes OOB

__device__ __forceinline__ float wave_max(float v) {
  #pragma unroll
  for (int off = 32; off; off >>= 1) v = fmaxf(v, __shfl_xor(v, off, 64));
  return v;
}
__device__ __forceinline__ float wave_sum(float v) {
  #pragma unroll
  for (int off = 32; off; off >>= 1) v += __shfl_xor(v, off, 64);
  return v;
}

// Pack coords + squared norm: pts[n] = {x, y, z, x^2+y^2+z^2}; pad with +inf norm
__global__ __launch_bounds__(256) void prep_kernel(const float* __restrict__ coord,
                                                   float4* __restrict__ pts) {
  int n = blockIdx.x * 256 + threadIdx.x;
  if (n >= PTS_PAD) return;
  if (n < NPTS) {
    float x = coord[n], y = coord[NPTS + n], z = coord[2 * NPTS + n];
    pts[n] = make_float4(x, y, z, x * x + y * y + z * z);
  } else {
    pts[n] = make_float4(0.f, 0.f, 0.f, INFINITY);  // pd = -inf, never inserts
  }
}

// One wave per query, full scan, 256 candidates per iteration (4 sub-blocks of 64).
// Wave-distributed sorted top-20: lane j holds j-th best by pd desc; ties -> lower
// index stays (matches jax.lax.top_k). thr (= current 20th best) is refreshed once
// per ballot only — it is purely a filter. Sub-threshold candidates self-insert
// into lanes >= 20 (overflow region, never emitted), so skipping the per-insert
// recheck/refresh preserves exact semantics while cutting the serial shuffle
// chain from 3 round trips per bit to 1. Fused: atomicAdd reverse-degree count.
__global__ __launch_bounds__(256) void knn_kernel(const float4* __restrict__ pts,
                                                  int* __restrict__ knn,
                                                  int* __restrict__ cnt) {
  int n = (blockIdx.x << 2) + (threadIdx.x >> 6);
  int lane = threadIdx.x & 63;
  float4 p = pts[n];
  float bd = -INFINITY;
  int bi = -1;
  float4 qc0 = pts[lane];
  float4 qc1 = pts[64 + lane];
  float4 qc2 = pts[128 + lane];
  float4 qc3 = pts[192 + lane];
  for (int it = 0; it < KIT; ++it) {
    int nb = (it + 1) * 256 + lane;
    float4 qn0 = pts[nb];
    float4 qn1 = pts[nb + 64];
    float4 qn2 = pts[nb + 128];
    float4 qn3 = pts[nb + 192];
    float pd[4];
    pd[0] = 2.f * (p.x * qc0.x + p.y * qc0.y + p.z * qc0.z) - p.w - qc0.w;
    pd[1] = 2.f * (p.x * qc1.x + p.y * qc1.y + p.z * qc1.z) - p.w - qc1.w;
    pd[2] = 2.f * (p.x * qc2.x + p.y * qc2.y + p.z * qc2.z) - p.w - qc2.w;
    pd[3] = 2.f * (p.x * qc3.x + p.y * qc3.y + p.z * qc3.z) - p.w - qc3.w;
    #pragma unroll
    for (int c = 0; c < 4; ++c) {
      float thr = __shfl(bd, KNN - 1, 64);            // refresh filter per ballot
      unsigned long long mask = __ballot(pd[c] > thr);
      while (mask) {
        int sl = (int)__builtin_ctzll(mask);          // lowest lane = lowest index
        mask &= mask - 1;
        float dc = __shfl(pd[c], sl, 64);             // these three shuffles are
        float dprev = __shfl_up(bd, 1, 64);           // mutually independent:
        int   iprev = __shfl_up(bi, 1, 64);           // chain depth = 1 round trip
        if (bd < dc) {                                // entries >= dc stay (stable ties)
          int ic = it * 256 + (c << 6) + sl;
          if (lane == 0 || dprev >= dc) { bd = dc; bi = ic; }
          else                          { bd = dprev; bi = iprev; }
        }
      }
    }
    qc0 = qn0; qc1 = qn1; qc2 = qn2; qc3 = qn3;
  }
  if (lane < KNN) {
    knn[n * KNN + lane] = bi;
    if (bi != n) atomicAdd(&cnt[bi], 1);       // fused reverse-degree count
  }
}

// Single-block exclusive scan, chunked.
__global__ __launch_bounds__(1024) void scan_kernel(const int* __restrict__ cnt,
                                                    int* __restrict__ rofs) {
  __shared__ int s[1024];
  int t = threadIdx.x;
  const int CH = 10;
  int b0 = t * CH;
  int loc = 0;
  #pragma unroll
  for (int i = 0; i < CH; ++i) {
    int idx = b0 + i;
    loc += (idx < NPTS) ? cnt[idx] : 0;
  }
  s[t] = loc;
  __syncthreads();
  for (int off = 1; off < 1024; off <<= 1) {
    int x = (t >= off) ? s[t - off] : 0;
    __syncthreads();
    s[t] += x;
    __syncthreads();
  }
  int pre = (t > 0) ? s[t - 1] : 0;
  if (t == 0) rofs[0] = 0;
  #pragma unroll
  for (int i = 0; i < CH; ++i) {
    int idx = b0 + i;
    if (idx < NPTS) { pre += cnt[idx]; rofs[idx + 1] = pre; }
  }
}

__global__ __launch_bounds__(256) void fill_kernel(const int* __restrict__ knn,
                                                   const int* __restrict__ rofs,
                                                   int* __restrict__ cur,
                                                   int* __restrict__ rev) {
  int i = blockIdx.x * 256 + threadIdx.x;
  if (i >= NPTS * KNN) return;
  int nn = i / KNN;
  int m = knn[i];
  if (m != nn) {
    int pos = atomicAdd(&cur[m], 1);
    rev[rofs[m] + pos] = nn;
  }
}

// Fused: h = x@W (32 rows/block, x staged in LDS, 4 rows/thread), emits fp16 h2
// + per-row attention scalars ssrc = h.a_s, sdst = h.a_d. No f32 h stored.
template<int DIN, int XCOL>
__global__ __launch_bounds__(256) void gemm_fused(const float* __restrict__ x,
                                                  const float* __restrict__ W,
                                                  const float* __restrict__ a_s,
                                                  const float* __restrict__ a_d,
                                                  __half* __restrict__ h2,
                                                  float* __restrict__ ssrc,
                                                  float* __restrict__ sdst) {
  __shared__ float xt[32 * (DIN + 1)];
  int t = threadIdx.x;
  int row0 = blockIdx.x * 32;
  if (XCOL) {  // x is [DIN][NPTS] (features)
    #pragma unroll
    for (int c = 0; c < DIN / 8; ++c) {
      int e = c * 256 + t;
      int k = e >> 5, r = e & 31;
      int row = row0 + r; if (row >= NPTS) row = NPTS - 1;
      xt[r * (DIN + 1) + k] = x[k * NPTS + row];
    }
  } else {     // x is [NPTS][128]
    #pragma unroll
    for (int c = 0; c < DIN / 8; ++c) {
      int e = c * 256 + t;
      int r = e >> 7, k = e & 127;
      int row = row0 + r; if (row >= NPTS) row = NPTS - 1;
      xt[r * (DIN + 1) + k] = x[row * DIN + k];
    }
  }
  __syncthreads();
  int g = t >> 5;              // 0..7
  int c4 = (t & 31) << 2;      // 0..124
  float4 as4 = *(const float4*)(a_s + c4);
  float4 ad4 = *(const float4*)(a_d + c4);
  float4 acc[4];
  #pragma unroll
  for (int i = 0; i < 4; ++i) acc[i] = make_float4(0.f, 0.f, 0.f, 0.f);
  #pragma unroll 8
  for (int k = 0; k < DIN; ++k) {
    float4 wv = *(const float4*)(W + k * F + c4);
    #pragma unroll
    for (int i = 0; i < 4; ++i) {
      float xv = xt[(g + 8 * i) * (DIN + 1) + k];   // broadcast within group
      acc[i].x = fmaf(xv, wv.x, acc[i].x);
      acc[i].y = fmaf(xv, wv.y, acc[i].y);
      acc[i].z = fmaf(xv, wv.z, acc[i].z);
      acc[i].w = fmaf(xv, wv.w, acc[i].w);
    }
  }
  #pragma unroll
  for (int i = 0; i < 4; ++i) {
    int row = row0 + g + 8 * i;
    float sa = acc[i].x * as4.x + acc[i].y * as4.y + acc[i].z * as4.z + acc[i].w * as4.w;
    float sd = acc[i].x * ad4.x + acc[i].y * ad4.y + acc[i].z * ad4.z + acc[i].w * ad4.w;
    #pragma unroll
    for (int off = 16; off; off >>= 1) {   // reduce within the 32-lane group
      sa += __shfl_xor(sa, off, 64);
      sd += __shfl_xor(sd, off, 64);
    }
    if (row < NPTS) {
      __half2 pa = __floats2half2_rn(acc[i].x, acc[i].y);
      __half2 pb = __floats2half2_rn(acc[i].z, acc[i].w);
      union { __half2 h[2]; float2 f; } u;
      u.h[0] = pa; u.h[1] = pb;
      *(float2*)(h2 + row * F + c4) = u.f;
      if ((t & 31) == 0) { ssrc[row] = sa; sdst[row] = sd; }
    }
  }
}

// One wave per dst node; softmax over edge multiset then PV gather from fp16 h2.
__global__ __launch_bounds__(256) void attn_kernel(const __half* __restrict__ h2,
                                                   const float* __restrict__ ssrc,
                                                   const float* __restrict__ sdst,
                                                   const int* __restrict__ knn,
                                                   const int* __restrict__ rofs,
                                                   const int* __restrict__ rev,
                                                   const float* __restrict__ bias,
                                                   float* __restrict__ xout) {
  int n = (blockIdx.x * 256 + threadIdx.x) >> 6;
  int lane = threadIdx.x & 63;
  float sdn = sdst[n];
  int rb = rofs[n];
  int rcnt = rofs[n + 1] - rb;
  int T = KNN + rcnt + 1;
  float buf[8];
  int srcr[8];
  float mymax = -INFINITY;
  #pragma unroll
  for (int it = 0; it < 8; ++it) {
    int t = it * 64 + lane;
    int src = n;
    bool valid = false;
    if (t < T) {
      if (t < KNN)             { src = knn[n * KNN + t]; valid = (src != n); }
      else if (t < KNN + rcnt) { src = rev[rb + t - KNN]; valid = true; }
      else                     { src = n;                 valid = true; }
    }
    srcr[it] = src;
    float lg = -INFINITY;
    if (valid) {
      lg = ssrc[src] + sdn;
      lg = (lg > 0.f) ? lg : 0.2f * lg;   // leaky_relu
      mymax = fmaxf(mymax, lg);
    }
    buf[it] = lg;
  }
  mymax = wave_max(mymax);
  float s = 0.f;
  #pragma unroll
  for (int it = 0; it < 8; ++it) {
    float e = (buf[it] == -INFINITY) ? 0.f : expf(buf[it] - mymax);
    buf[it] = e;
    s += e;
  }
  s = wave_sum(s);
  float inv = 1.f / s;

  float2 acc = make_float2(0.f, 0.f);
  const __half2* hb = (const __half2*)h2 + lane;   // lane's half2 within each row
  for (int it = 0; it < 8 && it * 64 < T; ++it) {
    int tmax = T - it * 64;
    if (tmax > 64) tmax = 64;
    for (int lt = 0; lt < tmax; lt += 4) {
      float w0 = __shfl(buf[it], lt + 0, 64);
      float w1 = __shfl(buf[it], lt + 1, 64);
      float w2 = __shfl(buf[it], lt + 2, 64);
      float w3 = __shfl(buf[it], lt + 3, 64);
      int   s0 = __shfl(srcr[it], lt + 0, 64);
      int   s1 = __shfl(srcr[it], lt + 1, 64);
      int   s2 = __shfl(srcr[it], lt + 2, 64);
      int   s3 = __shfl(srcr[it], lt + 3, 64);
      float2 h0 = __half22float2(hb[s0 * 64]);
      float2 h1 = __half22float2(hb[s1 * 64]);
      float2 h2v = __half22float2(hb[s2 * 64]);
      float2 h3 = __half22float2(hb[s3 * 64]);
      acc.x = fmaf(w0, h0.x, acc.x);  acc.y = fmaf(w0, h0.y, acc.y);
      acc.x = fmaf(w1, h1.x, acc.x);  acc.y = fmaf(w1, h1.y, acc.y);
      acc.x = fmaf(w2, h2v.x, acc.x); acc.y = fmaf(w2, h2v.y, acc.y);
      acc.x = fmaf(w3, h3.x, acc.x);  acc.y = fmaf(w3, h3.y, acc.y);
    }
  }
  int d = 2 * lane;
  float2 o;
  o.x = fmaf(acc.x, inv, bias[d]);
  o.y = fmaf(acc.y, inv, bias[d + 1]);
  *(float2*)(xout + n * F + d) = o;
}

// d_out[d*NPTS + n] = x[n*F + d]
__global__ __launch_bounds__(256) void transpose_kernel(const float* __restrict__ x,
                                                        float* __restrict__ out) {
  __shared__ float s[32][129];
  int n0 = blockIdx.x * 32;
  int t = threadIdx.x;
  int col = t & 127;
  int r0 = t >> 7;
  #pragma unroll
  for (int i = 0; i < 16; ++i) {
    int row = r0 + i * 2;
    int n = n0 + row;
    s[row][col] = (n < NPTS) ? x[n * F + col] : 0.f;
  }
  __syncthreads();
  int nl = t & 31, d0 = t >> 5;
  int n = n0 + nl;
  if (n < NPTS) {
    #pragma unroll
    for (int j = 0; j < 16; ++j) {
      int d = d0 * 16 + j;
      out[d * NPTS + n] = s[nl][d];
    }
  }
}

extern "C" void kernel_launch(void* const* d_in, const int* in_sizes, int n_in,
                              void* d_out, int out_size, void* d_ws, size_t ws_size,
                              hipStream_t stream) {
  const float* coord = (const float*)d_in[0];
  const float* feat  = (const float*)d_in[1];
  const float* W1  = (const float*)d_in[2];
  const float* as1 = (const float*)d_in[3];
  const float* ad1 = (const float*)d_in[4];
  const float* b1  = (const float*)d_in[5];
  const float* W2  = (const float*)d_in[6];
  const float* as2 = (const float*)d_in[7];
  const float* ad2 = (const float*)d_in[8];
  const float* b2  = (const float*)d_in[9];
  const float* W3  = (const float*)d_in[10];
  const float* as3 = (const float*)d_in[11];
  const float* ad3 = (const float*)d_in[12];
  const float* b3  = (const float*)d_in[13];

  char* ws = (char*)d_ws;
  float4* pts = (float4*)(ws + 0);            //   167936 B (padded to 10496)
  int* knn  = (int*)(ws + 167936);            //   800000 B
  int* cnt  = (int*)(ws + 967936);            //    40000 B
  int* cur  = (int*)(ws + 1007936);           //    40000 B (contiguous with cnt)
  int* rofs = (int*)(ws + 1047936);           //    40016 B
  int* rev  = (int*)(ws + 1087952);           //   800000 B
  __half* h2  = (__half*)(ws + 1887952);      //  2560000 B
  float* ssrc = (float*)(ws + 4447952);       //    40000 B
  float* sdst = (float*)(ws + 4487952);       //    40000 B
  float* xbuf = (float*)(ws + 4527952);       //  5120000 B -> end 9647952

  hipMemsetAsync(cnt, 0, 80000, stream);      // cnt + cur (before knn's atomics)
  prep_kernel<<<(PTS_PAD + 255) / 256, 256, 0, stream>>>(coord, pts);
  knn_kernel<<<NPTS / 4, 256, 0, stream>>>(pts, knn, cnt);
  scan_kernel<<<1, 1024, 0, stream>>>(cnt, rofs);
  fill_kernel<<<(NPTS * KNN + 255) / 256, 256, 0, stream>>>(knn, rofs, cur, rev);

  gemm_fused<64, 1><<<(NPTS + 31) / 32, 256, 0, stream>>>(feat, W1, as1, ad1, h2, ssrc, sdst);
  attn_kernel<<<NPTS / 4, 256, 0, stream>>>(h2, ssrc, sdst, knn, rofs, rev, b1, xbuf);
  gemm_fused<128, 0><<<(NPTS + 31) / 32, 256, 0, stream>>>(xbuf, W2, as2, ad2, h2, ssrc, sdst);
  attn_kernel<<<NPTS / 4, 256, 0, stream>>>(h2, ssrc, sdst, knn, rofs, rev, b2, xbuf);
  gemm_fused<128, 0><<<(NPTS + 31) / 32, 256, 0, stream>>>(xbuf, W3, as3, ad3, h2, ssrc, sdst);
  attn_kernel<<<NPTS / 4, 256, 0, stream>>>(h2, ssrc, sdst, knn, rofs, rev, b3, xbuf);

  transpose_kernel<<<(NPTS + 31) / 32, 256, 0, stream>>>(xbuf, (float*)d_out);
}

// Round 13
// 280.480 us; speedup vs baseline: 1.0347x; 1.0347x over previous
//
#include <hip/hip_runtime.h>
#include <hip/hip_fp16.h>
#include <math.h>

#define NPTS 10000
#define KNN  20
#define F    128
#define KIT  40            // iterations of 256 candidates
#define PTS_PAD 10496      // KIT*256 + 256 so prefetch never goes OOB

__device__ __forceinline__ float wave_max(float v) {
  #pragma unroll
  for (int off = 32; off; off >>= 1) v = fmaxf(v, __shfl_xor(v, off, 64));
  return v;
}
__device__ __forceinline__ float wave_sum(float v) {
  #pragma unroll
  for (int off = 32; off; off >>= 1) v += __shfl_xor(v, off, 64);
  return v;
}

// Pack coords + squared norm; pad with +inf norm. Also zeroes cnt+cur (20000 ints).
__global__ __launch_bounds__(256) void prep_kernel(const float* __restrict__ coord,
                                                   float4* __restrict__ pts,
                                                   int* __restrict__ cntcur) {
  int n = blockIdx.x * 256 + threadIdx.x;
  if (n < 2 * NPTS) cntcur[n] = 0;
  if (n >= PTS_PAD) return;
  if (n < NPTS) {
    float x = coord[n], y = coord[NPTS + n], z = coord[2 * NPTS + n];
    pts[n] = make_float4(x, y, z, x * x + y * y + z * z);
  } else {
    pts[n] = make_float4(0.f, 0.f, 0.f, INFINITY);  // pd = -inf, never inserts
  }
}

// One wave per query, full scan, 256 candidates per iteration (4 sub-blocks of 64).
// Wave-distributed sorted top-20: lane j holds j-th best by pd desc; ties -> lower
// index stays (matches jax.lax.top_k). thr is a pure filter (sub-threshold
// candidates self-insert into overflow lanes >= 20, never emitted). Iteration 0
// refreshes thr per ballot (ramps from -inf); later iterations refresh once --
// staler thr only admits a few extra cheap inserts, semantics exact.
__global__ __launch_bounds__(256) void knn_kernel(const float4* __restrict__ pts,
                                                  int* __restrict__ knn,
                                                  int* __restrict__ cnt) {
  int n = (blockIdx.x << 2) + (threadIdx.x >> 6);
  int lane = threadIdx.x & 63;
  float4 p = pts[n];
  float bd = -INFINITY;
  int bi = -1;
  float4 qc0 = pts[lane];
  float4 qc1 = pts[64 + lane];
  float4 qc2 = pts[128 + lane];
  float4 qc3 = pts[192 + lane];
  for (int it = 0; it < KIT; ++it) {
    int nb = (it + 1) * 256 + lane;
    float4 qn0 = pts[nb];
    float4 qn1 = pts[nb + 64];
    float4 qn2 = pts[nb + 128];
    float4 qn3 = pts[nb + 192];
    float pd[4];
    pd[0] = 2.f * (p.x * qc0.x + p.y * qc0.y + p.z * qc0.z) - p.w - qc0.w;
    pd[1] = 2.f * (p.x * qc1.x + p.y * qc1.y + p.z * qc1.z) - p.w - qc1.w;
    pd[2] = 2.f * (p.x * qc2.x + p.y * qc2.y + p.z * qc2.z) - p.w - qc2.w;
    pd[3] = 2.f * (p.x * qc3.x + p.y * qc3.y + p.z * qc3.z) - p.w - qc3.w;
    float thr = __shfl(bd, KNN - 1, 64);              // once per iteration (it>0)
    #pragma unroll
    for (int c = 0; c < 4; ++c) {
      if (it == 0) thr = __shfl(bd, KNN - 1, 64);     // ramp-up phase: per ballot
      unsigned long long mask = __ballot(pd[c] > thr);
      while (mask) {
        int sl = (int)__builtin_ctzll(mask);          // lowest lane = lowest index
        mask &= mask - 1;
        float dc = __shfl(pd[c], sl, 64);             // these three shuffles are
        float dprev = __shfl_up(bd, 1, 64);           // mutually independent:
        int   iprev = __shfl_up(bi, 1, 64);           // chain depth = 1 round trip
        if (bd < dc) {                                // entries >= dc stay (stable ties)
          int ic = it * 256 + (c << 6) + sl;
          if (lane == 0 || dprev >= dc) { bd = dc; bi = ic; }
          else                          { bd = dprev; bi = iprev; }
        }
      }
    }
    qc0 = qn0; qc1 = qn1; qc2 = qn2; qc3 = qn3;
  }
  if (lane < KNN) {
    knn[n * KNN + lane] = bi;
    if (bi != n) atomicAdd(&cnt[bi], 1);       // fused reverse-degree count
  }
}

// Single-block exclusive scan, chunked.
__global__ __launch_bounds__(1024) void scan_kernel(const int* __restrict__ cnt,
                                                    int* __restrict__ rofs) {
  __shared__ int s[1024];
  int t = threadIdx.x;
  const int CH = 10;
  int b0 = t * CH;
  int loc = 0;
  #pragma unroll
  for (int i = 0; i < CH; ++i) {
    int idx = b0 + i;
    loc += (idx < NPTS) ? cnt[idx] : 0;
  }
  s[t] = loc;
  __syncthreads();
  for (int off = 1; off < 1024; off <<= 1) {
    int x = (t >= off) ? s[t - off] : 0;
    __syncthreads();
    s[t] += x;
    __syncthreads();
  }
  int pre = (t > 0) ? s[t - 1] : 0;
  if (t == 0) rofs[0] = 0;
  #pragma unroll
  for (int i = 0; i < CH; ++i) {
    int idx = b0 + i;
    if (idx < NPTS) { pre += cnt[idx]; rofs[idx + 1] = pre; }
  }
}

__global__ __launch_bounds__(256) void fill_kernel(const int* __restrict__ knn,
                                                   const int* __restrict__ rofs,
                                                   int* __restrict__ cur,
                                                   int* __restrict__ rev) {
  int i = blockIdx.x * 256 + threadIdx.x;
  if (i >= NPTS * KNN) return;
  int nn = i / KNN;
  int m = knn[i];
  if (m != nn) {
    int pos = atomicAdd(&cur[m], 1);
    rev[rofs[m] + pos] = nn;
  }
}

// Fused: h = x@W (32 rows/block, x staged in LDS, 4 rows/thread), emits fp16 h2
// + per-row attention scalars ssrc = h.a_s, sdst = h.a_d. No f32 h stored.
template<int DIN, int XCOL>
__global__ __launch_bounds__(256) void gemm_fused(const float* __restrict__ x,
                                                  const float* __restrict__ W,
                                                  const float* __restrict__ a_s,
                                                  const float* __restrict__ a_d,
                                                  __half* __restrict__ h2,
                                                  float* __restrict__ ssrc,
                                                  float* __restrict__ sdst) {
  __shared__ float xt[32 * (DIN + 1)];
  int t = threadIdx.x;
  int row0 = blockIdx.x * 32;
  if (XCOL) {  // x is [DIN][NPTS] (features)
    #pragma unroll
    for (int c = 0; c < DIN / 8; ++c) {
      int e = c * 256 + t;
      int k = e >> 5, r = e & 31;
      int row = row0 + r; if (row >= NPTS) row = NPTS - 1;
      xt[r * (DIN + 1) + k] = x[k * NPTS + row];
    }
  } else {     // x is [NPTS][128]
    #pragma unroll
    for (int c = 0; c < DIN / 8; ++c) {
      int e = c * 256 + t;
      int r = e >> 7, k = e & 127;
      int row = row0 + r; if (row >= NPTS) row = NPTS - 1;
      xt[r * (DIN + 1) + k] = x[row * DIN + k];
    }
  }
  __syncthreads();
  int g = t >> 5;              // 0..7
  int c4 = (t & 31) << 2;      // 0..124
  float4 as4 = *(const float4*)(a_s + c4);
  float4 ad4 = *(const float4*)(a_d + c4);
  float4 acc[4];
  #pragma unroll
  for (int i = 0; i < 4; ++i) acc[i] = make_float4(0.f, 0.f, 0.f, 0.f);
  #pragma unroll 8
  for (int k = 0; k < DIN; ++k) {
    float4 wv = *(const float4*)(W + k * F + c4);
    #pragma unroll
    for (int i = 0; i < 4; ++i) {
      float xv = xt[(g + 8 * i) * (DIN + 1) + k];   // broadcast within group
      acc[i].x = fmaf(xv, wv.x, acc[i].x);
      acc[i].y = fmaf(xv, wv.y, acc[i].y);
      acc[i].z = fmaf(xv, wv.z, acc[i].z);
      acc[i].w = fmaf(xv, wv.w, acc[i].w);
    }
  }
  #pragma unroll
  for (int i = 0; i < 4; ++i) {
    int row = row0 + g + 8 * i;
    float sa = acc[i].x * as4.x + acc[i].y * as4.y + acc[i].z * as4.z + acc[i].w * as4.w;
    float sd = acc[i].x * ad4.x + acc[i].y * ad4.y + acc[i].z * ad4.z + acc[i].w * ad4.w;
    #pragma unroll
    for (int off = 16; off; off >>= 1) {   // reduce within the 32-lane group
      sa += __shfl_xor(sa, off, 64);
      sd += __shfl_xor(sd, off, 64);
    }
    if (row < NPTS) {
      __half2 pa = __floats2half2_rn(acc[i].x, acc[i].y);
      __half2 pb = __floats2half2_rn(acc[i].z, acc[i].w);
      union { __half2 h[2]; float2 f; } u;
      u.h[0] = pa; u.h[1] = pb;
      *(float2*)(h2 + row * F + c4) = u.f;
      if ((t & 31) == 0) { ssrc[row] = sa; sdst[row] = sd; }
    }
  }
}

// One wave per dst node; softmax over edge multiset then PV gather from fp16 h2.
// Phase 2: (weight, src) staged per-wave in LDS -> uniform broadcast reads, no
// shuffle round-trip chains, 8 independent h2 gathers in flight.
__global__ __launch_bounds__(256) void attn_kernel(const __half* __restrict__ h2,
                                                   const float* __restrict__ ssrc,
                                                   const float* __restrict__ sdst,
                                                   const int* __restrict__ knn,
                                                   const int* __restrict__ rofs,
                                                   const int* __restrict__ rev,
                                                   const float* __restrict__ bias,
                                                   float* __restrict__ xout) {
  __shared__ float wls[4][512];
  __shared__ int   sls[4][512];
  int wv = threadIdx.x >> 6;
  int n = (blockIdx.x * 256 + threadIdx.x) >> 6;
  int lane = threadIdx.x & 63;
  float sdn = sdst[n];
  int rb = rofs[n];
  int rcnt = rofs[n + 1] - rb;
  int T = KNN + rcnt + 1;          // assumed <= 512
  float buf[8];
  float mymax = -INFINITY;
  #pragma unroll
  for (int it = 0; it < 8; ++it) {
    int t = it * 64 + lane;
    int src = n;
    bool valid = false;
    if (t < T) {
      if (t < KNN)             { src = knn[n * KNN + t]; valid = (src != n); }
      else if (t < KNN + rcnt) { src = rev[rb + t - KNN]; valid = true; }
      else                     { src = n;                 valid = true; }
    }
    sls[wv][t] = src;
    float lg = -INFINITY;
    if (valid) {
      lg = ssrc[src] + sdn;
      lg = (lg > 0.f) ? lg : 0.2f * lg;   // leaky_relu
      mymax = fmaxf(mymax, lg);
    }
    buf[it] = lg;
  }
  mymax = wave_max(mymax);
  float s = 0.f;
  #pragma unroll
  for (int it = 0; it < 8; ++it) {
    float e = (buf[it] == -INFINITY) ? 0.f : expf(buf[it] - mymax);
    wls[wv][it * 64 + lane] = e;     // invalid / out-of-range slots hold 0
    s += e;
  }
  s = wave_sum(s);
  float inv = 1.f / s;

  // Phase 2: wave reads its own LDS section (uniform address = broadcast).
  float2 acc = make_float2(0.f, 0.f);
  const __half2* hb = (const __half2*)h2 + lane;   // lane's half2 within each row
  int t = 0;
  for (; t + 8 <= T; t += 8) {
    float w[8]; int sx[8];
    #pragma unroll
    for (int j = 0; j < 8; ++j) { w[j] = wls[wv][t + j]; sx[j] = sls[wv][t + j]; }
    float2 hv[8];
    #pragma unroll
    for (int j = 0; j < 8; ++j) hv[j] = __half22float2(hb[sx[j] * 64]);
    #pragma unroll
    for (int j = 0; j < 8; ++j) {
      acc.x = fmaf(w[j], hv[j].x, acc.x);
      acc.y = fmaf(w[j], hv[j].y, acc.y);
    }
  }
  for (; t < T; ++t) {
    float w = wls[wv][t]; int sx = sls[wv][t];
    float2 hv = __half22float2(hb[sx * 64]);
    acc.x = fmaf(w, hv.x, acc.x);
    acc.y = fmaf(w, hv.y, acc.y);
  }
  int d = 2 * lane;
  float2 o;
  o.x = fmaf(acc.x, inv, bias[d]);
  o.y = fmaf(acc.y, inv, bias[d + 1]);
  *(float2*)(xout + n * F + d) = o;
}

// d_out[d*NPTS + n] = x[n*F + d]
__global__ __launch_bounds__(256) void transpose_kernel(const float* __restrict__ x,
                                                        float* __restrict__ out) {
  __shared__ float s[32][129];
  int n0 = blockIdx.x * 32;
  int t = threadIdx.x;
  int col = t & 127;
  int r0 = t >> 7;
  #pragma unroll
  for (int i = 0; i < 16; ++i) {
    int row = r0 + i * 2;
    int n = n0 + row;
    s[row][col] = (n < NPTS) ? x[n * F + col] : 0.f;
  }
  __syncthreads();
  int nl = t & 31, d0 = t >> 5;
  int n = n0 + nl;
  if (n < NPTS) {
    #pragma unroll
    for (int j = 0; j < 16; ++j) {
      int d = d0 * 16 + j;
      out[d * NPTS + n] = s[nl][d];
    }
  }
}

extern "C" void kernel_launch(void* const* d_in, const int* in_sizes, int n_in,
                              void* d_out, int out_size, void* d_ws, size_t ws_size,
                              hipStream_t stream) {
  const float* coord = (const float*)d_in[0];
  const float* feat  = (const float*)d_in[1];
  const float* W1  = (const float*)d_in[2];
  const float* as1 = (const float*)d_in[3];
  const float* ad1 = (const float*)d_in[4];
  const float* b1  = (const float*)d_in[5];
  const float* W2  = (const float*)d_in[6];
  const float* as2 = (const float*)d_in[7];
  const float* ad2 = (const float*)d_in[8];
  const float* b2  = (const float*)d_in[9];
  const float* W3  = (const float*)d_in[10];
  const float* as3 = (const float*)d_in[11];
  const float* ad3 = (const float*)d_in[12];
  const float* b3  = (const float*)d_in[13];

  char* ws = (char*)d_ws;
  float4* pts = (float4*)(ws + 0);            //   167936 B (padded to 10496)
  int* knn  = (int*)(ws + 167936);            //   800000 B
  int* cnt  = (int*)(ws + 967936);            //    40000 B
  int* cur  = (int*)(ws + 1007936);           //    40000 B (contiguous with cnt)
  int* rofs = (int*)(ws + 1047936);           //    40016 B
  int* rev  = (int*)(ws + 1087952);           //   800000 B
  __half* h2  = (__half*)(ws + 1887952);      //  2560000 B
  float* ssrc = (float*)(ws + 4447952);       //    40000 B
  float* sdst = (float*)(ws + 4487952);       //    40000 B
  float* xbuf = (float*)(ws + 4527952);       //  5120000 B -> end 9647952

  prep_kernel<<<(2 * NPTS + 255) / 256, 256, 0, stream>>>(coord, pts, cnt);
  knn_kernel<<<NPTS / 4, 256, 0, stream>>>(pts, knn, cnt);
  scan_kernel<<<1, 1024, 0, stream>>>(cnt, rofs);
  fill_kernel<<<(NPTS * KNN + 255) / 256, 256, 0, stream>>>(knn, rofs, cur, rev);

  gemm_fused<64, 1><<<(NPTS + 31) / 32, 256, 0, stream>>>(feat, W1, as1, ad1, h2, ssrc, sdst);
  attn_kernel<<<NPTS / 4, 256, 0, stream>>>(h2, ssrc, sdst, knn, rofs, rev, b1, xbuf);
  gemm_fused<128, 0><<<(NPTS + 31) / 32, 256, 0, stream>>>(xbuf, W2, as2, ad2, h2, ssrc, sdst);
  attn_kernel<<<NPTS / 4, 256, 0, stream>>>(h2, ssrc, sdst, knn, rofs, rev, b2, xbuf);
  gemm_fused<128, 0><<<(NPTS + 31) / 32, 256, 0, stream>>>(xbuf, W3, as3, ad3, h2, ssrc, sdst);
  attn_kernel<<<NPTS / 4, 256, 0, stream>>>(h2, ssrc, sdst, knn, rofs, rev, b3, xbuf);

  transpose_kernel<<<(NPTS + 31) / 32, 256, 0, stream>>>(xbuf, (float*)d_out);
}

// Round 14
// 271.534 us; speedup vs baseline: 1.0687x; 1.0329x over previous
//
#include <hip/hip_runtime.h>
#include <hip/hip_fp16.h>
#include <math.h>

#define NPTS 10000
#define KNN  20
#define F    128
#define KIT  40            // iterations of 256 candidates
#define PTS_PAD 10496      // KIT*256 + 256 so prefetch never goes OOB

__device__ __forceinline__ float wave_max(float v) {
  #pragma unroll
  for (int off = 32; off; off >>= 1) v = fmaxf(v, __shfl_xor(v, off, 64));
  return v;
}
__device__ __forceinline__ float wave_sum(float v) {
  #pragma unroll
  for (int off = 32; off; off >>= 1) v += __shfl_xor(v, off, 64);
  return v;
}

// Pack coords + squared norm; pad with +inf norm. Also zeroes cnt+cur (20000 ints).
__global__ __launch_bounds__(256) void prep_kernel(const float* __restrict__ coord,
                                                   float4* __restrict__ pts,
                                                   int* __restrict__ cntcur) {
  int n = blockIdx.x * 256 + threadIdx.x;
  if (n < 2 * NPTS) cntcur[n] = 0;
  if (n >= PTS_PAD) return;
  if (n < NPTS) {
    float x = coord[n], y = coord[NPTS + n], z = coord[2 * NPTS + n];
    pts[n] = make_float4(x, y, z, x * x + y * y + z * z);
  } else {
    pts[n] = make_float4(0.f, 0.f, 0.f, INFINITY);  // pd = -inf, never inserts
  }
}

// One wave per query, full scan, 256 candidates per iteration (4 sub-blocks of 64).
// Wave-distributed sorted top-20: lane j holds j-th best by (pd desc, idx asc) --
// identical order to jax.lax.top_k. Preseed: exact bitonic sort of candidates
// 0..63 (replaces the serial thr=-inf ramp). thr is a pure filter (sub-threshold
// candidates self-insert into overflow lanes >= 20, never emitted); refreshed per
// ballot in iteration 0, once per iteration after. Fused reverse-degree count.
__global__ __launch_bounds__(256) void knn_kernel(const float4* __restrict__ pts,
                                                  int* __restrict__ knn,
                                                  int* __restrict__ cnt) {
  int n = (blockIdx.x << 2) + (threadIdx.x >> 6);
  int lane = threadIdx.x & 63;
  float4 p = pts[n];
  float bd;
  int bi;
  // ---- preseed: sort candidates 0..63 by (pd desc, idx asc), lane j = j-th best
  {
    float4 q = pts[lane];
    bd = 2.f * (p.x * q.x + p.y * q.y + p.z * q.z) - p.w - q.w;
    bi = lane;
    #pragma unroll
    for (int k = 2; k <= 64; k <<= 1) {
      #pragma unroll
      for (int j = k >> 1; j > 0; j >>= 1) {
        float opd = __shfl_xor(bd, j, 64);
        int   oidx = __shfl_xor(bi, j, 64);
        bool iPre  = (bd > opd) || (bd == opd && bi < oidx); // I precede other
        bool lower = (lane & j) == 0;
        bool up    = (lane & k) == 0;
        bool keep  = up ? (lower == iPre) : (lower != iPre);
        if (!keep) { bd = opd; bi = oidx; }
      }
    }
  }
  float thr = __shfl(bd, KNN - 1, 64);
  float4 qc0 = pts[lane];
  float4 qc1 = pts[64 + lane];
  float4 qc2 = pts[128 + lane];
  float4 qc3 = pts[192 + lane];
  for (int it = 0; it < KIT; ++it) {
    int nb = (it + 1) * 256 + lane;
    float4 qn0 = pts[nb];
    float4 qn1 = pts[nb + 64];
    float4 qn2 = pts[nb + 128];
    float4 qn3 = pts[nb + 192];
    float pd[4];
    pd[0] = 2.f * (p.x * qc0.x + p.y * qc0.y + p.z * qc0.z) - p.w - qc0.w;
    pd[1] = 2.f * (p.x * qc1.x + p.y * qc1.y + p.z * qc1.z) - p.w - qc1.w;
    pd[2] = 2.f * (p.x * qc2.x + p.y * qc2.y + p.z * qc2.z) - p.w - qc2.w;
    pd[3] = 2.f * (p.x * qc3.x + p.y * qc3.y + p.z * qc3.z) - p.w - qc3.w;
    if (it > 0) thr = __shfl(bd, KNN - 1, 64);        // once per iteration
    #pragma unroll
    for (int c = 0; c < 4; ++c) {
      if (it == 0) {
        if (c == 0) continue;                         // handled by preseed sort
        thr = __shfl(bd, KNN - 1, 64);                // ramp phase: per ballot
      }
      unsigned long long mask = __ballot(pd[c] > thr);
      while (mask) {
        int sl = (int)__builtin_ctzll(mask);          // lowest lane = lowest index
        mask &= mask - 1;
        float dc = __shfl(pd[c], sl, 64);             // these three shuffles are
        float dprev = __shfl_up(bd, 1, 64);           // mutually independent:
        int   iprev = __shfl_up(bi, 1, 64);           // chain depth = 1 round trip
        if (bd < dc) {                                // entries >= dc stay (stable ties)
          int ic = it * 256 + (c << 6) + sl;
          if (lane == 0 || dprev >= dc) { bd = dc; bi = ic; }
          else                          { bd = dprev; bi = iprev; }
        }
      }
    }
    qc0 = qn0; qc1 = qn1; qc2 = qn2; qc3 = qn3;
  }
  if (lane < KNN) {
    knn[n * KNN + lane] = bi;
    if (bi != n) atomicAdd(&cnt[bi], 1);       // fused reverse-degree count
  }
}

// Single-block exclusive scan, chunked.
__global__ __launch_bounds__(1024) void scan_kernel(const int* __restrict__ cnt,
                                                    int* __restrict__ rofs) {
  __shared__ int s[1024];
  int t = threadIdx.x;
  const int CH = 10;
  int b0 = t * CH;
  int loc = 0;
  #pragma unroll
  for (int i = 0; i < CH; ++i) {
    int idx = b0 + i;
    loc += (idx < NPTS) ? cnt[idx] : 0;
  }
  s[t] = loc;
  __syncthreads();
  for (int off = 1; off < 1024; off <<= 1) {
    int x = (t >= off) ? s[t - off] : 0;
    __syncthreads();
    s[t] += x;
    __syncthreads();
  }
  int pre = (t > 0) ? s[t - 1] : 0;
  if (t == 0) rofs[0] = 0;
  #pragma unroll
  for (int i = 0; i < CH; ++i) {
    int idx = b0 + i;
    if (idx < NPTS) { pre += cnt[idx]; rofs[idx + 1] = pre; }
  }
}

__global__ __launch_bounds__(256) void fill_kernel(const int* __restrict__ knn,
                                                   const int* __restrict__ rofs,
                                                   int* __restrict__ cur,
                                                   int* __restrict__ rev) {
  int i = blockIdx.x * 256 + threadIdx.x;
  if (i >= NPTS * KNN) return;
  int nn = i / KNN;
  int m = knn[i];
  if (m != nn) {
    int pos = atomicAdd(&cur[m], 1);
    rev[rofs[m] + pos] = nn;
  }
}

// Fused: h = x@W (32 rows/block, x staged in LDS, 4 rows/thread), emits fp16 h2
// + per-row attention scalars ssrc = h.a_s, sdst = h.a_d. LDS reads are b128
// (pad 132 floats keeps 16B alignment; staging-write conflict 4-way, negligible).
template<int DIN, int XCOL>
__global__ __launch_bounds__(256) void gemm_fused(const float* __restrict__ x,
                                                  const float* __restrict__ W,
                                                  const float* __restrict__ a_s,
                                                  const float* __restrict__ a_d,
                                                  __half* __restrict__ h2,
                                                  float* __restrict__ ssrc,
                                                  float* __restrict__ sdst) {
  __shared__ float xt[32 * (DIN + 4)];
  int t = threadIdx.x;
  int row0 = blockIdx.x * 32;
  if (XCOL) {  // x is [DIN][NPTS] (features)
    #pragma unroll
    for (int c = 0; c < DIN / 8; ++c) {
      int e = c * 256 + t;
      int k = e >> 5, r = e & 31;
      int row = row0 + r; if (row >= NPTS) row = NPTS - 1;
      xt[r * (DIN + 4) + k] = x[k * NPTS + row];
    }
  } else {     // x is [NPTS][128]
    #pragma unroll
    for (int c = 0; c < DIN / 8; ++c) {
      int e = c * 256 + t;
      int r = e >> 7, k = e & 127;
      int row = row0 + r; if (row >= NPTS) row = NPTS - 1;
      xt[r * (DIN + 4) + k] = x[row * DIN + k];
    }
  }
  __syncthreads();
  int g = t >> 5;              // 0..7
  int c4 = (t & 31) << 2;      // 0..124
  float4 as4 = *(const float4*)(a_s + c4);
  float4 ad4 = *(const float4*)(a_d + c4);
  float4 acc[4];
  #pragma unroll
  for (int i = 0; i < 4; ++i) acc[i] = make_float4(0.f, 0.f, 0.f, 0.f);
  #pragma unroll 2
  for (int k = 0; k < DIN; k += 4) {
    float4 wv0 = *(const float4*)(W + k * F + c4);
    float4 wv1 = *(const float4*)(W + (k + 1) * F + c4);
    float4 wv2 = *(const float4*)(W + (k + 2) * F + c4);
    float4 wv3 = *(const float4*)(W + (k + 3) * F + c4);
    #pragma unroll
    for (int i = 0; i < 4; ++i) {
      float4 xv = *(const float4*)(xt + (g + 8 * i) * (DIN + 4) + k);  // b128 broadcast
      acc[i].x = fmaf(xv.x, wv0.x, acc[i].x);
      acc[i].y = fmaf(xv.x, wv0.y, acc[i].y);
      acc[i].z = fmaf(xv.x, wv0.z, acc[i].z);
      acc[i].w = fmaf(xv.x, wv0.w, acc[i].w);
      acc[i].x = fmaf(xv.y, wv1.x, acc[i].x);
      acc[i].y = fmaf(xv.y, wv1.y, acc[i].y);
      acc[i].z = fmaf(xv.y, wv1.z, acc[i].z);
      acc[i].w = fmaf(xv.y, wv1.w, acc[i].w);
      acc[i].x = fmaf(xv.z, wv2.x, acc[i].x);
      acc[i].y = fmaf(xv.z, wv2.y, acc[i].y);
      acc[i].z = fmaf(xv.z, wv2.z, acc[i].z);
      acc[i].w = fmaf(xv.z, wv2.w, acc[i].w);
      acc[i].x = fmaf(xv.w, wv3.x, acc[i].x);
      acc[i].y = fmaf(xv.w, wv3.y, acc[i].y);
      acc[i].z = fmaf(xv.w, wv3.z, acc[i].z);
      acc[i].w = fmaf(xv.w, wv3.w, acc[i].w);
    }
  }
  #pragma unroll
  for (int i = 0; i < 4; ++i) {
    int row = row0 + g + 8 * i;
    float sa = acc[i].x * as4.x + acc[i].y * as4.y + acc[i].z * as4.z + acc[i].w * as4.w;
    float sd = acc[i].x * ad4.x + acc[i].y * ad4.y + acc[i].z * ad4.z + acc[i].w * ad4.w;
    #pragma unroll
    for (int off = 16; off; off >>= 1) {   // reduce within the 32-lane group
      sa += __shfl_xor(sa, off, 64);
      sd += __shfl_xor(sd, off, 64);
    }
    if (row < NPTS) {
      __half2 pa = __floats2half2_rn(acc[i].x, acc[i].y);
      __half2 pb = __floats2half2_rn(acc[i].z, acc[i].w);
      union { __half2 h[2]; float2 f; } u;
      u.h[0] = pa; u.h[1] = pb;
      *(float2*)(h2 + row * F + c4) = u.f;
      if ((t & 31) == 0) { ssrc[row] = sa; sdst[row] = sd; }
    }
  }
}

// One wave per dst node; softmax over edge multiset then PV gather from fp16 h2.
// Phase 2: (weight, src) staged per-wave in LDS -> uniform broadcast reads, no
// shuffle round-trip chains, 8 independent h2 gathers in flight.
__global__ __launch_bounds__(256) void attn_kernel(const __half* __restrict__ h2,
                                                   const float* __restrict__ ssrc,
                                                   const float* __restrict__ sdst,
                                                   const int* __restrict__ knn,
                                                   const int* __restrict__ rofs,
                                                   const int* __restrict__ rev,
                                                   const float* __restrict__ bias,
                                                   float* __restrict__ xout) {
  __shared__ float wls[4][512];
  __shared__ int   sls[4][512];
  int wv = threadIdx.x >> 6;
  int n = (blockIdx.x * 256 + threadIdx.x) >> 6;
  int lane = threadIdx.x & 63;
  float sdn = sdst[n];
  int rb = rofs[n];
  int rcnt = rofs[n + 1] - rb;
  int T = KNN + rcnt + 1;          // assumed <= 512
  float buf[8];
  float mymax = -INFINITY;
  #pragma unroll
  for (int it = 0; it < 8; ++it) {
    int t = it * 64 + lane;
    int src = n;
    bool valid = false;
    if (t < T) {
      if (t < KNN)             { src = knn[n * KNN + t]; valid = (src != n); }
      else if (t < KNN + rcnt) { src = rev[rb + t - KNN]; valid = true; }
      else                     { src = n;                 valid = true; }
    }
    sls[wv][t] = src;
    float lg = -INFINITY;
    if (valid) {
      lg = ssrc[src] + sdn;
      lg = (lg > 0.f) ? lg : 0.2f * lg;   // leaky_relu
      mymax = fmaxf(mymax, lg);
    }
    buf[it] = lg;
  }
  mymax = wave_max(mymax);
  float s = 0.f;
  #pragma unroll
  for (int it = 0; it < 8; ++it) {
    float e = (buf[it] == -INFINITY) ? 0.f : expf(buf[it] - mymax);
    wls[wv][it * 64 + lane] = e;     // invalid / out-of-range slots hold 0
    s += e;
  }
  s = wave_sum(s);
  float inv = 1.f / s;

  // Phase 2: wave reads its own LDS section (uniform address = broadcast).
  float2 acc = make_float2(0.f, 0.f);
  const __half2* hb = (const __half2*)h2 + lane;   // lane's half2 within each row
  int t = 0;
  for (; t + 8 <= T; t += 8) {
    float w[8]; int sx[8];
    #pragma unroll
    for (int j = 0; j < 8; ++j) { w[j] = wls[wv][t + j]; sx[j] = sls[wv][t + j]; }
    float2 hv[8];
    #pragma unroll
    for (int j = 0; j < 8; ++j) hv[j] = __half22float2(hb[sx[j] * 64]);
    #pragma unroll
    for (int j = 0; j < 8; ++j) {
      acc.x = fmaf(w[j], hv[j].x, acc.x);
      acc.y = fmaf(w[j], hv[j].y, acc.y);
    }
  }
  for (; t < T; ++t) {
    float w = wls[wv][t]; int sx = sls[wv][t];
    float2 hv = __half22float2(hb[sx * 64]);
    acc.x = fmaf(w, hv.x, acc.x);
    acc.y = fmaf(w, hv.y, acc.y);
  }
  int d = 2 * lane;
  float2 o;
  o.x = fmaf(acc.x, inv, bias[d]);
  o.y = fmaf(acc.y, inv, bias[d + 1]);
  *(float2*)(xout + n * F + d) = o;
}

// d_out[d*NPTS + n] = x[n*F + d]
__global__ __launch_bounds__(256) void transpose_kernel(const float* __restrict__ x,
                                                        float* __restrict__ out) {
  __shared__ float s[32][129];
  int n0 = blockIdx.x * 32;
  int t = threadIdx.x;
  int col = t & 127;
  int r0 = t >> 7;
  #pragma unroll
  for (int i = 0; i < 16; ++i) {
    int row = r0 + i * 2;
    int n = n0 + row;
    s[row][col] = (n < NPTS) ? x[n * F + col] : 0.f;
  }
  __syncthreads();
  int nl = t & 31, d0 = t >> 5;
  int n = n0 + nl;
  if (n < NPTS) {
    #pragma unroll
    for (int j = 0; j < 16; ++j) {
      int d = d0 * 16 + j;
      out[d * NPTS + n] = s[nl][d];
    }
  }
}

extern "C" void kernel_launch(void* const* d_in, const int* in_sizes, int n_in,
                              void* d_out, int out_size, void* d_ws, size_t ws_size,
                              hipStream_t stream) {
  const float* coord = (const float*)d_in[0];
  const float* feat  = (const float*)d_in[1];
  const float* W1  = (const float*)d_in[2];
  const float* as1 = (const float*)d_in[3];
  const float* ad1 = (const float*)d_in[4];
  const float* b1  = (const float*)d_in[5];
  const float* W2  = (const float*)d_in[6];
  const float* as2 = (const float*)d_in[7];
  const float* ad2 = (const float*)d_in[8];
  const float* b2  = (const float*)d_in[9];
  const float* W3  = (const float*)d_in[10];
  const float* as3 = (const float*)d_in[11];
  const float* ad3 = (const float*)d_in[12];
  const float* b3  = (const float*)d_in[13];

  char* ws = (char*)d_ws;
  float4* pts = (float4*)(ws + 0);            //   167936 B (padded to 10496)
  int* knn  = (int*)(ws + 167936);            //   800000 B
  int* cnt  = (int*)(ws + 967936);            //    40000 B
  int* cur  = (int*)(ws + 1007936);           //    40000 B (contiguous with cnt)
  int* rofs = (int*)(ws + 1047936);           //    40016 B
  int* rev  = (int*)(ws + 1087952);           //   800000 B
  __half* h2  = (__half*)(ws + 1887952);      //  2560000 B
  float* ssrc = (float*)(ws + 4447952);       //    40000 B
  float* sdst = (float*)(ws + 4487952);       //    40000 B
  float* xbuf = (float*)(ws + 4527952);       //  5120000 B -> end 9647952

  prep_kernel<<<(2 * NPTS + 255) / 256, 256, 0, stream>>>(coord, pts, cnt);
  knn_kernel<<<NPTS / 4, 256, 0, stream>>>(pts, knn, cnt);
  scan_kernel<<<1, 1024, 0, stream>>>(cnt, rofs);
  fill_kernel<<<(NPTS * KNN + 255) / 256, 256, 0, stream>>>(knn, rofs, cur, rev);

  gemm_fused<64, 1><<<(NPTS + 31) / 32, 256, 0, stream>>>(feat, W1, as1, ad1, h2, ssrc, sdst);
  attn_kernel<<<NPTS / 4, 256, 0, stream>>>(h2, ssrc, sdst, knn, rofs, rev, b1, xbuf);
  gemm_fused<128, 0><<<(NPTS + 31) / 32, 256, 0, stream>>>(xbuf, W2, as2, ad2, h2, ssrc, sdst);
  attn_kernel<<<NPTS / 4, 256, 0, stream>>>(h2, ssrc, sdst, knn, rofs, rev, b2, xbuf);
  gemm_fused<128, 0><<<(NPTS + 31) / 32, 256, 0, stream>>>(xbuf, W3, as3, ad3, h2, ssrc, sdst);
  attn_kernel<<<NPTS / 4, 256, 0, stream>>>(h2, ssrc, sdst, knn, rofs, rev, b3, xbuf);

  transpose_kernel<<<(NPTS + 31) / 32, 256, 0, stream>>>(xbuf, (float*)d_out);
}